// Round 2
// baseline (525.172 us; speedup 1.0000x reference)
//
#include <hip/hip_runtime.h>

#define N_NODES 8192
#define IN_F 512
#define OUT_F 64
#define LOG2E 1.4426950408889634f

typedef short bf16x8 __attribute__((ext_vector_type(8)));
typedef float f32x4 __attribute__((ext_vector_type(4)));

static __device__ __forceinline__ unsigned short f2bf(float f) {
  unsigned u = __float_as_uint(f);
  u = (u + 0x7fffu + ((u >> 16) & 1u)) >> 16;
  return (unsigned short)u;
}

// K0: pack adj (int32 0/1) into a bitmask. Bit b of u32 word w <-> flat
// element 32*w + b. Pure streaming: 256 MB read, 8 MB written.
__global__ __launch_bounds__(256) void k_pack(const int* __restrict__ adj,
                                              unsigned* __restrict__ mask) {
  __shared__ unsigned char nib[256];
  const int tid = threadIdx.x;
  for (int it = 0; it < 16; ++it) {
    int g4 = blockIdx.x * (256 * 16) + it * 256 + tid;
    int4 v = ((const int4*)adj)[g4];
    unsigned n = (unsigned)(v.x != 0) | ((unsigned)(v.y != 0) << 1) |
                 ((unsigned)(v.z != 0) << 2) | ((unsigned)(v.w != 0) << 3);
    __syncthreads();  // previous iteration's reads complete
    nib[tid] = (unsigned char)n;
    __syncthreads();
    if (tid < 32) {
      unsigned w = 0;
#pragma unroll
      for (int i = 0; i < 8; ++i) w |= ((unsigned)nib[tid * 8 + i]) << (4 * i);
      mask[blockIdx.x * 512 + it * 32 + tid] = w;
    }
  }
}

// K1: h = input @ W  (one wave per row, lane = output col), plus
// f_srcL = (h@a[:64])*log2e, f_dstL = (h@a[64:])*log2e via wave reduction.
__global__ __launch_bounds__(256) void k_gemm(const float* __restrict__ input,
                                              const float* __restrict__ W,
                                              const float* __restrict__ a,
                                              float* __restrict__ h,
                                              float* __restrict__ fsrcL,
                                              float* __restrict__ fdstL) {
  const int lane = threadIdx.x & 63;
  const int wv = threadIdx.x >> 6;
  const int row = blockIdx.x * 4 + wv;
  const float* inrow = input + (size_t)row * IN_F;
  const int c = lane;
  float acc = 0.f;
  for (int k = 0; k < IN_F; k += 4) {
    float4 x = *(const float4*)(inrow + k);
    acc += x.x * W[(k + 0) * OUT_F + c];
    acc += x.y * W[(k + 1) * OUT_F + c];
    acc += x.z * W[(k + 2) * OUT_F + c];
    acc += x.w * W[(k + 3) * OUT_F + c];
  }
  h[(size_t)row * OUT_F + c] = acc;
  float vs = acc * a[c];
  float vd = acc * a[OUT_F + c];
#pragma unroll
  for (int off = 32; off > 0; off >>= 1) {
    vs += __shfl_xor(vs, off, 64);
    vd += __shfl_xor(vd, off, 64);
  }
  if (lane == 0) {
    fsrcL[row] = vs * LOG2E;
    fdstL[row] = vd * LOG2E;
  }
}

// K1c: ML = max(f_dstL)  (single block)
__global__ __launch_bounds__(256) void k_max(const float* __restrict__ fdstL,
                                             float* __restrict__ ML) {
  float m = -3.0e38f;
  for (int i = threadIdx.x; i < N_NODES; i += 256) m = fmaxf(m, fdstL[i]);
#pragma unroll
  for (int off = 32; off > 0; off >>= 1) m = fmaxf(m, __shfl_xor(m, off, 64));
  __shared__ float sm[4];
  if ((threadIdx.x & 63) == 0) sm[threadIdx.x >> 6] = m;
  __syncthreads();
  if (threadIdx.x == 0) ML[0] = fmaxf(fmaxf(sm[0], sm[1]), fmaxf(sm[2], sm[3]));
}

// K1b: hT[c][r] = bf16(h[r][c])  — 64x64 tiles through padded LDS.
__global__ __launch_bounds__(256) void k_transpose(const float* __restrict__ h,
                                                   unsigned short* __restrict__ hT) {
  __shared__ float t[64][65];
  const int r0 = blockIdx.x * 64;
#pragma unroll
  for (int q = 0; q < 16; q++) {
    int idx = q * 256 + threadIdx.x;
    int r = idx >> 6, c = idx & 63;
    t[c][r] = h[(size_t)(r0 + r) * OUT_F + c];
  }
  __syncthreads();
#pragma unroll
  for (int q = 0; q < 8; q++) {
    int idx = q * 256 + threadIdx.x;
    int c = idx >> 5, rp = idx & 31;
    float a0 = t[c][2 * rp], a1 = t[c][2 * rp + 1];
    unsigned pk = (unsigned)f2bf(a0) | ((unsigned)f2bf(a1) << 16);
    *(unsigned*)(hT + (size_t)c * N_NODES + r0 + 2 * rp) = pk;
  }
}

// K2: attention. Block = 16 rows, 8 waves each covering 1/8 of the j-range.
// adj comes in as a bitmask (one u64 per row per 64-j window, broadcast
// across the 4 k-group lanes). P computed directly in MFMA A-layout.
__global__ __launch_bounds__(512) void k_attn(const unsigned long long* __restrict__ mask,
                                              const unsigned short* __restrict__ hT,
                                              const float* __restrict__ fsrcL,
                                              const float* __restrict__ fdstL,
                                              const float* __restrict__ MLp,
                                              float* __restrict__ out) {
  const int lane = threadIdx.x & 63;
  const int wv = threadIdx.x >> 6;  // 0..7
  const int i0 = blockIdx.x * 16;
  const int m = lane & 15;  // A-row / B-col index
  const int g = lane >> 4;  // k-group 0..3

  const float MLv = MLp[0];
  const float fs = fsrcL[i0 + m];
  const float xm = fs + MLv;
  const float mL = fmaxf(xm, 0.2f * xm);  // fixed per-row max (log2-scaled)

  f32x4 acc0{}, acc1{}, acc2{}, acc3{};
  float lpart = 0.f;

  const unsigned long long* mrow = mask + (size_t)(i0 + m) * (N_NODES / 64);
  const unsigned short* hT0 = hT + (size_t)m * N_NODES;

  const int jbeg = wv * (N_NODES / 8);
  const int jend = jbeg + (N_NODES / 8);
  for (int j0 = jbeg; j0 < jend; j0 += 64) {
    unsigned long long M = mrow[j0 >> 6];
#pragma unroll
    for (int s = 0; s < 2; s++) {
      const int jb = j0 + s * 32 + g * 8;
      float4 d0 = *(const float4*)(fdstL + jb);
      float4 d1 = *(const float4*)(fdstL + jb + 4);
      bf16x8 b0 = *(const bf16x8*)(hT0 + jb);
      bf16x8 b1 = *(const bf16x8*)(hT0 + (size_t)16 * N_NODES + jb);
      bf16x8 b2 = *(const bf16x8*)(hT0 + (size_t)32 * N_NODES + jb);
      bf16x8 b3 = *(const bf16x8*)(hT0 + (size_t)48 * N_NODES + jb);

      unsigned mb = (unsigned)(M >> (s * 32 + g * 8)) & 0xffu;
      float dv[8] = {d0.x, d0.y, d0.z, d0.w, d1.x, d1.y, d1.z, d1.w};
      bf16x8 pa;
#pragma unroll
      for (int t = 0; t < 8; t++) {
        float x = fs + dv[t];
        float y = fmaxf(x, 0.2f * x) - mL;
        float p = __builtin_amdgcn_exp2f(y);
        p = (mb >> t) & 1u ? p : 0.0f;
        lpart += p;
        pa[t] = (short)f2bf(p);
      }
      acc0 = __builtin_amdgcn_mfma_f32_16x16x32_bf16(pa, b0, acc0, 0, 0, 0);
      acc1 = __builtin_amdgcn_mfma_f32_16x16x32_bf16(pa, b1, acc1, 0, 0, 0);
      acc2 = __builtin_amdgcn_mfma_f32_16x16x32_bf16(pa, b2, acc2, 0, 0, 0);
      acc3 = __builtin_amdgcn_mfma_f32_16x16x32_bf16(pa, b3, acc3, 0, 0, 0);
    }
  }

  // l: reduce across the 4 k-groups (lanes sharing m)
  lpart += __shfl_xor(lpart, 16, 64);
  lpart += __shfl_xor(lpart, 32, 64);

  __shared__ float accbuf[8][16][64];
  __shared__ float lbuf[8][16];
#pragma unroll
  for (int r = 0; r < 4; r++) {
    accbuf[wv][g * 4 + r][0 + m] = acc0[r];
    accbuf[wv][g * 4 + r][16 + m] = acc1[r];
    accbuf[wv][g * 4 + r][32 + m] = acc2[r];
    accbuf[wv][g * 4 + r][48 + m] = acc3[r];
  }
  if (lane < 16) lbuf[wv][lane] = lpart;
  __syncthreads();

#pragma unroll
  for (int q = 0; q < 2; q++) {
    int idx = q * 512 + threadIdx.x;
    int r = idx >> 6, c = idx & 63;
    float ssum = 0.f, l = 0.f;
#pragma unroll
    for (int w = 0; w < 8; w++) {
      ssum += accbuf[w][r][c];
      l += lbuf[w][r];
    }
    float v = ssum / l;
    out[(size_t)(i0 + r) * OUT_F + c] =
        v > 0.f ? v : __builtin_amdgcn_exp2f(v * LOG2E) - 1.f;
  }
}

extern "C" void kernel_launch(void* const* d_in, const int* in_sizes, int n_in,
                              void* d_out, int out_size, void* d_ws, size_t ws_size,
                              hipStream_t stream) {
  const float* input = (const float*)d_in[0];
  const int* adj = (const int*)d_in[1];
  const float* W = (const float*)d_in[2];
  const float* a = (const float*)d_in[3];
  float* out = (float*)d_out;

  char* ws = (char*)d_ws;
  float* h = (float*)ws;                                     // 2 MB
  unsigned short* hT = (unsigned short*)(ws + (2u << 20));   // 1 MB
  float* fsrcL = (float*)(ws + (3u << 20));                  // 32 KB
  float* fdstL = (float*)(ws + (3u << 20) + 32 * 1024);      // 32 KB
  float* ML = (float*)(ws + (3u << 20) + 64 * 1024);         // 4 B
  unsigned* mask = (unsigned*)(ws + (4u << 20));             // 8 MB

  k_pack<<<4096, 256, 0, stream>>>(adj, mask);
  k_gemm<<<N_NODES / 4, 256, 0, stream>>>(input, W, a, h, fsrcL, fdstL);
  k_max<<<1, 256, 0, stream>>>(fdstL, ML);
  k_transpose<<<N_NODES / 64, 256, 0, stream>>>(h, hT);
  k_attn<<<N_NODES / 16, 512, 0, stream>>>((const unsigned long long*)mask, hT,
                                           fsrcL, fdstL, ML, out);
}

// Round 4
// 516.373 us; speedup vs baseline: 1.0170x; 1.0170x over previous
//
#include <hip/hip_runtime.h>

#define N_NODES 8192
#define IN_F 512
#define OUT_F 64
#define LOG2E 1.4426950408889634f

typedef short bf16x8 __attribute__((ext_vector_type(8)));
typedef float f32x4 __attribute__((ext_vector_type(4)));
typedef int i32x4 __attribute__((ext_vector_type(4)));

// K1: h = input @ W (one wave per row, lane = output col). Writes hT (bf16,
// transposed, via LDS) and f_srcL/f_dstL (pre-scaled by log2e).
__global__ __launch_bounds__(256) void k_gemm(const float* __restrict__ input,
                                              const float* __restrict__ W,
                                              const float* __restrict__ a,
                                              unsigned short* __restrict__ hT,
                                              float* __restrict__ fsrcL,
                                              float* __restrict__ fdstL) {
  const int lane = threadIdx.x & 63;
  const int wv = threadIdx.x >> 6;
  const int r0 = blockIdx.x * 4;
  const int row = r0 + wv;
  const float* inrow = input + (size_t)row * IN_F;
  const int c = lane;
  float acc = 0.f;
  for (int k = 0; k < IN_F; k += 4) {
    float4 x = *(const float4*)(inrow + k);
    acc += x.x * W[(k + 0) * OUT_F + c];
    acc += x.y * W[(k + 1) * OUT_F + c];
    acc += x.z * W[(k + 2) * OUT_F + c];
    acc += x.w * W[(k + 3) * OUT_F + c];
  }
  float vs = acc * a[c];
  float vd = acc * a[OUT_F + c];
#pragma unroll
  for (int off = 32; off > 0; off >>= 1) {
    vs += __shfl_xor(vs, off, 64);
    vd += __shfl_xor(vd, off, 64);
  }
  if (lane == 0) {
    fsrcL[row] = vs * LOG2E;
    fdstL[row] = vd * LOG2E;
  }
  // transpose through LDS: hT[c][r0..r0+3] as 4 packed bf16 (8 B store)
  __shared__ float hs[4][64];
  hs[wv][c] = acc;
  __syncthreads();
  if (threadIdx.x < 64) {
    const int cc = threadIdx.x;
    unsigned u0 = __float_as_uint(hs[0][cc]) + 0x8000u;
    unsigned u1 = __float_as_uint(hs[1][cc]) + 0x8000u;
    unsigned u2 = __float_as_uint(hs[2][cc]) + 0x8000u;
    unsigned u3 = __float_as_uint(hs[3][cc]) + 0x8000u;
    uint2 pk;
    pk.x = __builtin_amdgcn_perm(u1, u0, 0x07060302u);  // [bf(u1)|bf(u0)]
    pk.y = __builtin_amdgcn_perm(u3, u2, 0x07060302u);
    *(uint2*)(hT + (size_t)cc * N_NODES + r0) = pk;
  }
}

// K1b: ML = max(fdstL); E1 = 2^fdstL; E2 = 2^(0.2*fdstL). Single block.
__global__ __launch_bounds__(256) void k_prep(const float* __restrict__ fdstL,
                                              float* __restrict__ ML,
                                              float* __restrict__ E1,
                                              float* __restrict__ E2) {
  float m = -3.0e38f;
  for (int i = threadIdx.x; i < N_NODES; i += 256) {
    float v = fdstL[i];
    E1[i] = __builtin_amdgcn_exp2f(v);
    E2[i] = __builtin_amdgcn_exp2f(0.2f * v);
    m = fmaxf(m, v);
  }
#pragma unroll
  for (int off = 32; off > 0; off >>= 1) m = fmaxf(m, __shfl_xor(m, off, 64));
  __shared__ float sm[4];
  if ((threadIdx.x & 63) == 0) sm[threadIdx.x >> 6] = m;
  __syncthreads();
  if (threadIdx.x == 0) ML[0] = fmaxf(fmaxf(sm[0], sm[1]), fmaxf(sm[2], sm[3]));
}

// K2: attention. Block = 16 rows, 8 waves, j split 8 ways. No exp in the
// hot loop: p = adj ? (E1_j>=T_i ? E1_j*S1_i : E2_j*S2_i) : 0.
// l comes from a 5th MFMA against an all-ones B fragment.
__global__ __launch_bounds__(512) void k_attn(const int* __restrict__ adj,
                                              const unsigned short* __restrict__ hT,
                                              const float* __restrict__ fsrcL,
                                              const float* __restrict__ MLp,
                                              const float* __restrict__ E1,
                                              const float* __restrict__ E2,
                                              float* __restrict__ out) {
  const int lane = threadIdx.x & 63;
  const int wv = threadIdx.x >> 6;  // 0..7
  const int i0 = blockIdx.x * 16;
  const int m = lane & 15;  // A-row / B-col index
  const int g = lane >> 4;  // k-group 0..3

  const float MLv = MLp[0];
  const float fs = fsrcL[i0 + m];
  const float xm = fs + MLv;
  const float mL = fmaxf(xm, 0.2f * xm);  // per-row max (log2 domain)
  const float S1 = __builtin_amdgcn_exp2f(fs - mL);
  const float S2 = __builtin_amdgcn_exp2f(0.2f * fs - mL);
  const float Ti = __builtin_amdgcn_exp2f(-fs);

  f32x4 acc0{}, acc1{}, acc2{}, acc3{}, acc4{};
  union { unsigned w[4]; bf16x8 v; } ones;
  ones.w[0] = ones.w[1] = ones.w[2] = ones.w[3] = 0x3F803F80u;

  const int* adjrow = adj + (size_t)(i0 + m) * N_NODES;
  const unsigned short* hT0 = hT + (size_t)m * N_NODES;

  const int jbeg = wv * (N_NODES / 8);
  for (int j0 = jbeg; j0 < jbeg + (N_NODES / 8); j0 += 64) {
#pragma unroll
    for (int s = 0; s < 2; s++) {
      const int jb = j0 + s * 32 + g * 8;
      i32x4 a0 = __builtin_nontemporal_load((const i32x4*)(adjrow + jb));
      i32x4 a1 = __builtin_nontemporal_load((const i32x4*)(adjrow + jb) + 1);
      float4 e1a = *(const float4*)(E1 + jb);
      float4 e1b = *(const float4*)(E1 + jb + 4);
      float4 e2a = *(const float4*)(E2 + jb);
      float4 e2b = *(const float4*)(E2 + jb + 4);
      bf16x8 b0 = *(const bf16x8*)(hT0 + jb);
      bf16x8 b1 = *(const bf16x8*)(hT0 + (size_t)16 * N_NODES + jb);
      bf16x8 b2 = *(const bf16x8*)(hT0 + (size_t)32 * N_NODES + jb);
      bf16x8 b3 = *(const bf16x8*)(hT0 + (size_t)48 * N_NODES + jb);

      const int av[8] = {a0.x, a0.y, a0.z, a0.w, a1.x, a1.y, a1.z, a1.w};
      const float e1v[8] = {e1a.x, e1a.y, e1a.z, e1a.w, e1b.x, e1b.y, e1b.z, e1b.w};
      const float e2v[8] = {e2a.x, e2a.y, e2a.z, e2a.w, e2b.x, e2b.y, e2b.z, e2b.w};
      unsigned u[8];
#pragma unroll
      for (int t = 0; t < 8; t++) {
        float p = (e1v[t] >= Ti) ? e1v[t] * S1 : e2v[t] * S2;
        p = av[t] ? p : 0.0f;
        u[t] = __float_as_uint(p) + 0x8000u;
      }
      union { unsigned w[4]; bf16x8 v; } pc;
      pc.w[0] = __builtin_amdgcn_perm(u[1], u[0], 0x07060302u);
      pc.w[1] = __builtin_amdgcn_perm(u[3], u[2], 0x07060302u);
      pc.w[2] = __builtin_amdgcn_perm(u[5], u[4], 0x07060302u);
      pc.w[3] = __builtin_amdgcn_perm(u[7], u[6], 0x07060302u);

      acc0 = __builtin_amdgcn_mfma_f32_16x16x32_bf16(pc.v, b0, acc0, 0, 0, 0);
      acc1 = __builtin_amdgcn_mfma_f32_16x16x32_bf16(pc.v, b1, acc1, 0, 0, 0);
      acc2 = __builtin_amdgcn_mfma_f32_16x16x32_bf16(pc.v, b2, acc2, 0, 0, 0);
      acc3 = __builtin_amdgcn_mfma_f32_16x16x32_bf16(pc.v, b3, acc3, 0, 0, 0);
      acc4 = __builtin_amdgcn_mfma_f32_16x16x32_bf16(pc.v, ones.v, acc4, 0, 0, 0);
    }
  }

  __shared__ float accbuf[8][16][64];
  __shared__ float lbuf[8][16];
#pragma unroll
  for (int r = 0; r < 4; r++) {
    accbuf[wv][g * 4 + r][0 + m]  = acc0[r];
    accbuf[wv][g * 4 + r][16 + m] = acc1[r];
    accbuf[wv][g * 4 + r][32 + m] = acc2[r];
    accbuf[wv][g * 4 + r][48 + m] = acc3[r];
  }
  if ((lane & 15) == 0) {
#pragma unroll
    for (int r = 0; r < 4; r++) lbuf[wv][g * 4 + r] = acc4[r];
  }
  __syncthreads();

#pragma unroll
  for (int q = 0; q < 2; q++) {
    int idx = q * 512 + threadIdx.x;
    int r = idx >> 6, c = idx & 63;
    float ssum = 0.f, l = 0.f;
#pragma unroll
    for (int w = 0; w < 8; w++) {
      ssum += accbuf[w][r][c];
      l += lbuf[w][r];
    }
    float v = ssum / l;
    out[(size_t)(i0 + r) * OUT_F + c] =
        v > 0.f ? v : __builtin_amdgcn_exp2f(v * LOG2E) - 1.f;
  }
}

extern "C" void kernel_launch(void* const* d_in, const int* in_sizes, int n_in,
                              void* d_out, int out_size, void* d_ws, size_t ws_size,
                              hipStream_t stream) {
  const float* input = (const float*)d_in[0];
  const int* adj = (const int*)d_in[1];
  const float* W = (const float*)d_in[2];
  const float* a = (const float*)d_in[3];
  float* out = (float*)d_out;

  char* ws = (char*)d_ws;
  unsigned short* hT = (unsigned short*)ws;                  // 1 MB
  float* fsrcL = (float*)(ws + (1u << 20));                  // 32 KB
  float* fdstL = (float*)(ws + (1u << 20) + 32 * 1024);      // 32 KB
  float* ML = (float*)(ws + (1u << 20) + 64 * 1024);         // 4 B
  float* E1 = (float*)(ws + (1u << 20) + 128 * 1024);        // 32 KB
  float* E2 = (float*)(ws + (1u << 20) + 160 * 1024);        // 32 KB

  k_gemm<<<N_NODES / 4, 256, 0, stream>>>(input, W, a, hT, fsrcL, fdstL);
  k_prep<<<1, 256, 0, stream>>>(fdstL, ML, E1, E2);
  k_attn<<<N_NODES / 16, 512, 0, stream>>>(adj, hT, fsrcL, ML, E1, E2, out);
}

// Round 5
// 511.393 us; speedup vs baseline: 1.0269x; 1.0097x over previous
//
#include <hip/hip_runtime.h>

#define N_NODES 8192
#define IN_F 512
#define OUT_F 64
#define LOG2E 1.4426950408889634f

typedef short bf16x8 __attribute__((ext_vector_type(8)));
typedef float f32x4 __attribute__((ext_vector_type(4)));

// K1: h = input @ W (one wave per row, lane = output col). Writes hT (bf16,
// transposed, via LDS) and f_srcL/f_dstL (pre-scaled by log2e).
__global__ __launch_bounds__(256) void k_gemm(const float* __restrict__ input,
                                              const float* __restrict__ W,
                                              const float* __restrict__ a,
                                              unsigned short* __restrict__ hT,
                                              float* __restrict__ fsrcL,
                                              float* __restrict__ fdstL) {
  const int lane = threadIdx.x & 63;
  const int wv = threadIdx.x >> 6;
  const int r0 = blockIdx.x * 4;
  const int row = r0 + wv;
  const float* inrow = input + (size_t)row * IN_F;
  const int c = lane;
  float acc = 0.f;
  for (int k = 0; k < IN_F; k += 4) {
    float4 x = *(const float4*)(inrow + k);
    acc += x.x * W[(k + 0) * OUT_F + c];
    acc += x.y * W[(k + 1) * OUT_F + c];
    acc += x.z * W[(k + 2) * OUT_F + c];
    acc += x.w * W[(k + 3) * OUT_F + c];
  }
  float vs = acc * a[c];
  float vd = acc * a[OUT_F + c];
#pragma unroll
  for (int off = 32; off > 0; off >>= 1) {
    vs += __shfl_xor(vs, off, 64);
    vd += __shfl_xor(vd, off, 64);
  }
  if (lane == 0) {
    fsrcL[row] = vs * LOG2E;
    fdstL[row] = vd * LOG2E;
  }
  // transpose through LDS: hT[c][r0..r0+3] as 4 packed bf16 (8 B store)
  __shared__ float hs[4][64];
  hs[wv][c] = acc;
  __syncthreads();
  if (threadIdx.x < 64) {
    const int cc = threadIdx.x;
    unsigned u0 = __float_as_uint(hs[0][cc]) + 0x8000u;
    unsigned u1 = __float_as_uint(hs[1][cc]) + 0x8000u;
    unsigned u2 = __float_as_uint(hs[2][cc]) + 0x8000u;
    unsigned u3 = __float_as_uint(hs[3][cc]) + 0x8000u;
    uint2 pk;
    pk.x = __builtin_amdgcn_perm(u1, u0, 0x07060302u);  // [bf(u1)|bf(u0)]
    pk.y = __builtin_amdgcn_perm(u3, u2, 0x07060302u);
    *(uint2*)(hT + (size_t)cc * N_NODES + r0) = pk;
  }
}

// K1c: ML = max(f_dstL)  (single block)
__global__ __launch_bounds__(256) void k_max(const float* __restrict__ fdstL,
                                             float* __restrict__ ML) {
  float m = -3.0e38f;
  for (int i = threadIdx.x; i < N_NODES; i += 256) m = fmaxf(m, fdstL[i]);
#pragma unroll
  for (int off = 32; off > 0; off >>= 1) m = fmaxf(m, __shfl_xor(m, off, 64));
  __shared__ float sm[4];
  if ((threadIdx.x & 63) == 0) sm[threadIdx.x >> 6] = m;
  __syncthreads();
  if (threadIdx.x == 0) ML[0] = fmaxf(fmaxf(sm[0], sm[1]), fmaxf(sm[2], sm[3]));
}

// K2: attention (R1-proven structure). Block = 16 rows, 8 waves, j split 8
// ways. P computed directly in MFMA A-layout (m=lane&15, k=(lane>>4)*8+t);
// exp2 in-loop from fdstL; plain cached adj loads; scalar l + shuffle.
__global__ __launch_bounds__(512) void k_attn(const int* __restrict__ adj,
                                              const unsigned short* __restrict__ hT,
                                              const float* __restrict__ fsrcL,
                                              const float* __restrict__ fdstL,
                                              const float* __restrict__ MLp,
                                              float* __restrict__ out) {
  const int lane = threadIdx.x & 63;
  const int wv = threadIdx.x >> 6;  // 0..7
  const int i0 = blockIdx.x * 16;
  const int m = lane & 15;  // A-row / B-col index
  const int g = lane >> 4;  // k-group 0..3

  const float MLv = MLp[0];
  const float fs = fsrcL[i0 + m];
  const float xm = fs + MLv;
  const float mL = fmaxf(xm, 0.2f * xm);  // fixed per-row max (log2 domain)

  f32x4 acc0{}, acc1{}, acc2{}, acc3{};
  float lpart = 0.f;

  const int* adjrow = adj + (size_t)(i0 + m) * N_NODES;
  const unsigned short* hT0 = hT + (size_t)m * N_NODES;

  const int jbeg = wv * (N_NODES / 8);
  for (int j0 = jbeg; j0 < jbeg + (N_NODES / 8); j0 += 64) {
#pragma unroll
    for (int s = 0; s < 2; s++) {
      const int jb = j0 + s * 32 + g * 8;
      int4 a0 = *(const int4*)(adjrow + jb);
      int4 a1 = *(const int4*)(adjrow + jb + 4);
      float4 d0 = *(const float4*)(fdstL + jb);
      float4 d1 = *(const float4*)(fdstL + jb + 4);
      bf16x8 b0 = *(const bf16x8*)(hT0 + jb);
      bf16x8 b1 = *(const bf16x8*)(hT0 + (size_t)16 * N_NODES + jb);
      bf16x8 b2 = *(const bf16x8*)(hT0 + (size_t)32 * N_NODES + jb);
      bf16x8 b3 = *(const bf16x8*)(hT0 + (size_t)48 * N_NODES + jb);

      const int av[8] = {a0.x, a0.y, a0.z, a0.w, a1.x, a1.y, a1.z, a1.w};
      const float dv[8] = {d0.x, d0.y, d0.z, d0.w, d1.x, d1.y, d1.z, d1.w};
      unsigned u[8];
#pragma unroll
      for (int t = 0; t < 8; t++) {
        float x = fs + dv[t];
        float y = fmaxf(x, 0.2f * x) - mL;
        float p = __builtin_amdgcn_exp2f(y);
        p = av[t] ? p : 0.0f;
        lpart += p;
        u[t] = __float_as_uint(p) + 0x8000u;
      }
      union { unsigned w[4]; bf16x8 v; } pc;
      pc.w[0] = __builtin_amdgcn_perm(u[1], u[0], 0x07060302u);
      pc.w[1] = __builtin_amdgcn_perm(u[3], u[2], 0x07060302u);
      pc.w[2] = __builtin_amdgcn_perm(u[5], u[4], 0x07060302u);
      pc.w[3] = __builtin_amdgcn_perm(u[7], u[6], 0x07060302u);

      acc0 = __builtin_amdgcn_mfma_f32_16x16x32_bf16(pc.v, b0, acc0, 0, 0, 0);
      acc1 = __builtin_amdgcn_mfma_f32_16x16x32_bf16(pc.v, b1, acc1, 0, 0, 0);
      acc2 = __builtin_amdgcn_mfma_f32_16x16x32_bf16(pc.v, b2, acc2, 0, 0, 0);
      acc3 = __builtin_amdgcn_mfma_f32_16x16x32_bf16(pc.v, b3, acc3, 0, 0, 0);
    }
  }

  // l: reduce across the 4 k-groups (lanes sharing m)
  lpart += __shfl_xor(lpart, 16, 64);
  lpart += __shfl_xor(lpart, 32, 64);

  __shared__ float accbuf[8][16][64];
  __shared__ float lbuf[8][16];
#pragma unroll
  for (int r = 0; r < 4; r++) {
    accbuf[wv][g * 4 + r][0 + m]  = acc0[r];
    accbuf[wv][g * 4 + r][16 + m] = acc1[r];
    accbuf[wv][g * 4 + r][32 + m] = acc2[r];
    accbuf[wv][g * 4 + r][48 + m] = acc3[r];
  }
  if (lane < 16) lbuf[wv][lane] = lpart;
  __syncthreads();

#pragma unroll
  for (int q = 0; q < 2; q++) {
    int idx = q * 512 + threadIdx.x;
    int r = idx >> 6, c = idx & 63;
    float ssum = 0.f, l = 0.f;
#pragma unroll
    for (int w = 0; w < 8; w++) {
      ssum += accbuf[w][r][c];
      l += lbuf[w][r];
    }
    float v = ssum / l;
    out[(size_t)(i0 + r) * OUT_F + c] =
        v > 0.f ? v : __builtin_amdgcn_exp2f(v * LOG2E) - 1.f;
  }
}

extern "C" void kernel_launch(void* const* d_in, const int* in_sizes, int n_in,
                              void* d_out, int out_size, void* d_ws, size_t ws_size,
                              hipStream_t stream) {
  const float* input = (const float*)d_in[0];
  const int* adj = (const int*)d_in[1];
  const float* W = (const float*)d_in[2];
  const float* a = (const float*)d_in[3];
  float* out = (float*)d_out;

  char* ws = (char*)d_ws;
  unsigned short* hT = (unsigned short*)ws;                  // 1 MB
  float* fsrcL = (float*)(ws + (1u << 20));                  // 32 KB
  float* fdstL = (float*)(ws + (1u << 20) + 32 * 1024);      // 32 KB
  float* ML = (float*)(ws + (1u << 20) + 64 * 1024);         // 4 B

  k_gemm<<<N_NODES / 4, 256, 0, stream>>>(input, W, a, hT, fsrcL, fdstL);
  k_max<<<1, 256, 0, stream>>>(fdstL, ML);
  k_attn<<<N_NODES / 16, 512, 0, stream>>>(adj, hT, fsrcL, fdstL, ML, out);
}

// Round 6
// 452.548 us; speedup vs baseline: 1.1605x; 1.1300x over previous
//
#include <hip/hip_runtime.h>

#define N_NODES 8192
#define IN_F 512
#define OUT_F 64
#define LOG2E 1.4426950408889634f
#define JSPLIT 4

typedef short bf16x8 __attribute__((ext_vector_type(8)));
typedef float f32x4 __attribute__((ext_vector_type(4)));

// K1: h = input @ W. 256 blocks x 4 waves; each wave computes 8 rows so W is
// read once per wave (8x less L2 traffic than 1 row/wave). x-row loads are
// wave-uniform (scalar-load eligible). Writes hT (bf16, transposed via LDS)
// and fsrcL/fdstL (pre-scaled by log2e).
__global__ __launch_bounds__(256) void k_gemm(const float* __restrict__ input,
                                              const float* __restrict__ W,
                                              const float* __restrict__ a,
                                              unsigned short* __restrict__ hT,
                                              float* __restrict__ fsrcL,
                                              float* __restrict__ fdstL) {
  const int lane = threadIdx.x & 63;
  const int wv = threadIdx.x >> 6;
  const int r0 = blockIdx.x * 32;
  const int rw = r0 + wv * 8;
  const int c = lane;
  float acc[8] = {0.f, 0.f, 0.f, 0.f, 0.f, 0.f, 0.f, 0.f};
  const float* Wc = W + c;
  for (int k = 0; k < IN_F; k += 4) {
    float w0 = Wc[(k + 0) * OUT_F];
    float w1 = Wc[(k + 1) * OUT_F];
    float w2 = Wc[(k + 2) * OUT_F];
    float w3 = Wc[(k + 3) * OUT_F];
#pragma unroll
    for (int r = 0; r < 8; r++) {
      float4 x = *(const float4*)(input + (size_t)(rw + r) * IN_F + k);
      acc[r] += x.x * w0 + x.y * w1 + x.z * w2 + x.w * w3;
    }
  }
#pragma unroll
  for (int r = 0; r < 8; r++) {
    float vs = acc[r] * a[c];
    float vd = acc[r] * a[OUT_F + c];
#pragma unroll
    for (int off = 32; off > 0; off >>= 1) {
      vs += __shfl_xor(vs, off, 64);
      vd += __shfl_xor(vd, off, 64);
    }
    if (lane == 0) {
      fsrcL[rw + r] = vs * LOG2E;
      fdstL[rw + r] = vd * LOG2E;
    }
  }
  // transpose through LDS (padded): hT[c][r0..r0+32) as 32 packed bf16
  __shared__ float hs[32][65];
#pragma unroll
  for (int r = 0; r < 8; r++) hs[wv * 8 + r][c] = acc[r];
  __syncthreads();
  {
    const int cc = threadIdx.x >> 2;  // 0..63
    const int q = threadIdx.x & 3;    // row-octet
    unsigned uu[8];
#pragma unroll
    for (int rr = 0; rr < 8; rr++)
      uu[rr] = __float_as_uint(hs[q * 8 + rr][cc]) + 0x8000u;
    uint4 pk;
    pk.x = __builtin_amdgcn_perm(uu[1], uu[0], 0x07060302u);
    pk.y = __builtin_amdgcn_perm(uu[3], uu[2], 0x07060302u);
    pk.z = __builtin_amdgcn_perm(uu[5], uu[4], 0x07060302u);
    pk.w = __builtin_amdgcn_perm(uu[7], uu[6], 0x07060302u);
    *(uint4*)(hT + (size_t)cc * N_NODES + r0 + q * 8) = pk;
  }
}

// K1c: ML = max(f_dstL)  (single block)
__global__ __launch_bounds__(256) void k_max(const float* __restrict__ fdstL,
                                             float* __restrict__ ML) {
  float m = -3.0e38f;
  for (int i = threadIdx.x; i < N_NODES; i += 256) m = fmaxf(m, fdstL[i]);
#pragma unroll
  for (int off = 32; off > 0; off >>= 1) m = fmaxf(m, __shfl_xor(m, off, 64));
  __shared__ float sm[4];
  if ((threadIdx.x & 63) == 0) sm[threadIdx.x >> 6] = m;
  __syncthreads();
  if (threadIdx.x == 0) ML[0] = fmaxf(fmaxf(sm[0], sm[1]), fmaxf(sm[2], sm[3]));
}

// K2: attention partials. Grid = 512 row-blocks x JSPLIT j-slabs (2048
// blocks, 4 waves each -> 8 blocks/CU, ~32 waves/CU). Each wave covers 512
// cols. All 16 VMEM loads of a 64-col window are issued before the compute.
// Writes num[js][i][c], den[js][i]; k_merge divides + ELU.
__global__ __launch_bounds__(256) void k_attn(const int* __restrict__ adj,
                                              const unsigned short* __restrict__ hT,
                                              const float* __restrict__ fsrcL,
                                              const float* __restrict__ fdstL,
                                              const float* __restrict__ MLp,
                                              float* __restrict__ num,
                                              float* __restrict__ den) {
  const int lane = threadIdx.x & 63;
  const int wv = threadIdx.x >> 6;  // 0..3
  const int rb = blockIdx.x >> 2;
  const int js = blockIdx.x & 3;
  const int i0 = rb * 16;
  const int m = lane & 15;  // A-row / B-col index
  const int g = lane >> 4;  // k-group 0..3

  const float MLv = MLp[0];
  const float fs = fsrcL[i0 + m];
  const float xm = fs + MLv;
  const float mL = fmaxf(xm, 0.2f * xm);  // fixed per-row max (log2 domain)

  f32x4 acc0{}, acc1{}, acc2{}, acc3{};
  float lpart = 0.f;

  const int* adjrow = adj + (size_t)(i0 + m) * N_NODES;
  const unsigned short* hT0 = hT + (size_t)m * N_NODES;

  const int jbeg = js * (N_NODES / JSPLIT) + wv * 512;
  for (int j0 = jbeg; j0 < jbeg + 512; j0 += 64) {
    const int jb0 = j0 + g * 8;
    const int jb1 = j0 + 32 + g * 8;
    // ---- all loads for this 64-col window ----
    int4 a00 = *(const int4*)(adjrow + jb0);
    int4 a01 = *(const int4*)(adjrow + jb0 + 4);
    int4 a10 = *(const int4*)(adjrow + jb1);
    int4 a11 = *(const int4*)(adjrow + jb1 + 4);
    float4 d00 = *(const float4*)(fdstL + jb0);
    float4 d01 = *(const float4*)(fdstL + jb0 + 4);
    float4 d10 = *(const float4*)(fdstL + jb1);
    float4 d11 = *(const float4*)(fdstL + jb1 + 4);
    bf16x8 b00 = *(const bf16x8*)(hT0 + jb0);
    bf16x8 b01 = *(const bf16x8*)(hT0 + (size_t)16 * N_NODES + jb0);
    bf16x8 b02 = *(const bf16x8*)(hT0 + (size_t)32 * N_NODES + jb0);
    bf16x8 b03 = *(const bf16x8*)(hT0 + (size_t)48 * N_NODES + jb0);
    bf16x8 b10 = *(const bf16x8*)(hT0 + jb1);
    bf16x8 b11 = *(const bf16x8*)(hT0 + (size_t)16 * N_NODES + jb1);
    bf16x8 b12 = *(const bf16x8*)(hT0 + (size_t)32 * N_NODES + jb1);
    bf16x8 b13 = *(const bf16x8*)(hT0 + (size_t)48 * N_NODES + jb1);
    // ---- compute s=0 ----
    {
      const int av[8] = {a00.x, a00.y, a00.z, a00.w, a01.x, a01.y, a01.z, a01.w};
      const float dv[8] = {d00.x, d00.y, d00.z, d00.w, d01.x, d01.y, d01.z, d01.w};
      unsigned u[8];
#pragma unroll
      for (int t = 0; t < 8; t++) {
        float x = fs + dv[t];
        float y = fmaxf(x, 0.2f * x) - mL;
        float p = __builtin_amdgcn_exp2f(y);
        p = av[t] ? p : 0.0f;
        lpart += p;
        u[t] = __float_as_uint(p) + 0x8000u;
      }
      union { unsigned w[4]; bf16x8 v; } pc;
      pc.w[0] = __builtin_amdgcn_perm(u[1], u[0], 0x07060302u);
      pc.w[1] = __builtin_amdgcn_perm(u[3], u[2], 0x07060302u);
      pc.w[2] = __builtin_amdgcn_perm(u[5], u[4], 0x07060302u);
      pc.w[3] = __builtin_amdgcn_perm(u[7], u[6], 0x07060302u);
      acc0 = __builtin_amdgcn_mfma_f32_16x16x32_bf16(pc.v, b00, acc0, 0, 0, 0);
      acc1 = __builtin_amdgcn_mfma_f32_16x16x32_bf16(pc.v, b01, acc1, 0, 0, 0);
      acc2 = __builtin_amdgcn_mfma_f32_16x16x32_bf16(pc.v, b02, acc2, 0, 0, 0);
      acc3 = __builtin_amdgcn_mfma_f32_16x16x32_bf16(pc.v, b03, acc3, 0, 0, 0);
    }
    // ---- compute s=1 ----
    {
      const int av[8] = {a10.x, a10.y, a10.z, a10.w, a11.x, a11.y, a11.z, a11.w};
      const float dv[8] = {d10.x, d10.y, d10.z, d10.w, d11.x, d11.y, d11.z, d11.w};
      unsigned u[8];
#pragma unroll
      for (int t = 0; t < 8; t++) {
        float x = fs + dv[t];
        float y = fmaxf(x, 0.2f * x) - mL;
        float p = __builtin_amdgcn_exp2f(y);
        p = av[t] ? p : 0.0f;
        lpart += p;
        u[t] = __float_as_uint(p) + 0x8000u;
      }
      union { unsigned w[4]; bf16x8 v; } pc;
      pc.w[0] = __builtin_amdgcn_perm(u[1], u[0], 0x07060302u);
      pc.w[1] = __builtin_amdgcn_perm(u[3], u[2], 0x07060302u);
      pc.w[2] = __builtin_amdgcn_perm(u[5], u[4], 0x07060302u);
      pc.w[3] = __builtin_amdgcn_perm(u[7], u[6], 0x07060302u);
      acc0 = __builtin_amdgcn_mfma_f32_16x16x32_bf16(pc.v, b10, acc0, 0, 0, 0);
      acc1 = __builtin_amdgcn_mfma_f32_16x16x32_bf16(pc.v, b11, acc1, 0, 0, 0);
      acc2 = __builtin_amdgcn_mfma_f32_16x16x32_bf16(pc.v, b12, acc2, 0, 0, 0);
      acc3 = __builtin_amdgcn_mfma_f32_16x16x32_bf16(pc.v, b13, acc3, 0, 0, 0);
    }
  }

  // l: reduce across the 4 k-groups (lanes sharing m)
  lpart += __shfl_xor(lpart, 16, 64);
  lpart += __shfl_xor(lpart, 32, 64);

  __shared__ float accbuf[4][16][64];
  __shared__ float lbuf[4][16];
#pragma unroll
  for (int r = 0; r < 4; r++) {
    accbuf[wv][g * 4 + r][0 + m]  = acc0[r];
    accbuf[wv][g * 4 + r][16 + m] = acc1[r];
    accbuf[wv][g * 4 + r][32 + m] = acc2[r];
    accbuf[wv][g * 4 + r][48 + m] = acc3[r];
  }
  if (lane < 16) lbuf[wv][lane] = lpart;
  __syncthreads();

#pragma unroll
  for (int q = 0; q < 4; q++) {
    int idx = q * 256 + threadIdx.x;
    int r = idx >> 6, c = idx & 63;
    float ssum = accbuf[0][r][c] + accbuf[1][r][c] + accbuf[2][r][c] + accbuf[3][r][c];
    num[((size_t)js * N_NODES + i0 + r) * OUT_F + c] = ssum;
  }
  if (threadIdx.x < 16) {
    den[(size_t)js * N_NODES + i0 + threadIdx.x] =
        lbuf[0][threadIdx.x] + lbuf[1][threadIdx.x] + lbuf[2][threadIdx.x] + lbuf[3][threadIdx.x];
  }
}

// K3: merge partials, divide, ELU.
__global__ __launch_bounds__(256) void k_merge(const float* __restrict__ num,
                                               const float* __restrict__ den,
                                               float* __restrict__ out) {
  const int idx = blockIdx.x * 256 + threadIdx.x;  // over N*OUT_F
  const int i = idx >> 6;
  float s = 0.f, l = 0.f;
#pragma unroll
  for (int js = 0; js < JSPLIT; js++) {
    s += num[((size_t)js * N_NODES) * OUT_F + idx];
    l += den[(size_t)js * N_NODES + i];
  }
  float v = s / l;
  out[idx] = v > 0.f ? v : __builtin_amdgcn_exp2f(v * LOG2E) - 1.f;
}

extern "C" void kernel_launch(void* const* d_in, const int* in_sizes, int n_in,
                              void* d_out, int out_size, void* d_ws, size_t ws_size,
                              hipStream_t stream) {
  const float* input = (const float*)d_in[0];
  const int* adj = (const int*)d_in[1];
  const float* W = (const float*)d_in[2];
  const float* a = (const float*)d_in[3];
  float* out = (float*)d_out;

  char* ws = (char*)d_ws;
  unsigned short* hT = (unsigned short*)ws;                  // 1 MB
  float* fsrcL = (float*)(ws + (1u << 20));                  // 32 KB
  float* fdstL = (float*)(ws + (1u << 20) + 32 * 1024);      // 32 KB
  float* ML = (float*)(ws + (1u << 20) + 64 * 1024);         // 4 B
  float* num = (float*)(ws + (2u << 20));                    // 8 MB
  float* den = (float*)(ws + (10u << 20));                   // 128 KB

  k_gemm<<<N_NODES / 32, 256, 0, stream>>>(input, W, a, hT, fsrcL, fdstL);
  k_max<<<1, 256, 0, stream>>>(fdstL, ML);
  k_attn<<<(N_NODES / 16) * JSPLIT, 256, 0, stream>>>(adj, hT, fsrcL, fdstL, ML, num, den);
  k_merge<<<N_NODES * OUT_F / 256, 256, 0, stream>>>(num, den, out);
}

// Round 7
// 450.392 us; speedup vs baseline: 1.1660x; 1.0048x over previous
//
#include <hip/hip_runtime.h>

#define N_NODES 8192
#define IN_F 512
#define OUT_F 64
#define LOG2E 1.4426950408889634f
#define JSPLIT 8

typedef short bf16x8 __attribute__((ext_vector_type(8)));
typedef float f32x4 __attribute__((ext_vector_type(4)));

// K1: h = input @ W. 512 blocks x 4 waves; each wave computes 4 rows
// (2 blocks/CU, 8 waves/CU). W reads are lane-striped (L2-resident);
// input-row loads are wave-uniform. Writes hT (bf16, transposed via LDS)
// and fsrcL/fdstL (pre-scaled by log2e).
__global__ __launch_bounds__(256) void k_gemm(const float* __restrict__ input,
                                              const float* __restrict__ W,
                                              const float* __restrict__ a,
                                              unsigned short* __restrict__ hT,
                                              float* __restrict__ fsrcL,
                                              float* __restrict__ fdstL) {
  const int lane = threadIdx.x & 63;
  const int wv = threadIdx.x >> 6;
  const int r0 = blockIdx.x * 16;
  const int rw = r0 + wv * 4;
  const int c = lane;
  float acc[4] = {0.f, 0.f, 0.f, 0.f};
  const float* Wc = W + c;
  for (int k = 0; k < IN_F; k += 4) {
    float w0 = Wc[(k + 0) * OUT_F];
    float w1 = Wc[(k + 1) * OUT_F];
    float w2 = Wc[(k + 2) * OUT_F];
    float w3 = Wc[(k + 3) * OUT_F];
#pragma unroll
    for (int r = 0; r < 4; r++) {
      float4 x = *(const float4*)(input + (size_t)(rw + r) * IN_F + k);
      acc[r] += x.x * w0 + x.y * w1 + x.z * w2 + x.w * w3;
    }
  }
#pragma unroll
  for (int r = 0; r < 4; r++) {
    float vs = acc[r] * a[c];
    float vd = acc[r] * a[OUT_F + c];
#pragma unroll
    for (int off = 32; off > 0; off >>= 1) {
      vs += __shfl_xor(vs, off, 64);
      vd += __shfl_xor(vd, off, 64);
    }
    if (lane == 0) {
      fsrcL[rw + r] = vs * LOG2E;
      fdstL[rw + r] = vd * LOG2E;
    }
  }
  // transpose through LDS (padded): hT[c][r0..r0+16) as 16 packed bf16
  __shared__ float hs[16][65];
#pragma unroll
  for (int r = 0; r < 4; r++) hs[wv * 4 + r][c] = acc[r];
  __syncthreads();
  {
    const int cc = threadIdx.x >> 2;  // 0..63
    const int q = threadIdx.x & 3;    // row-quad
    unsigned uu[4];
#pragma unroll
    for (int rr = 0; rr < 4; rr++)
      uu[rr] = __float_as_uint(hs[q * 4 + rr][cc]) + 0x8000u;
    uint2 pk;
    pk.x = __builtin_amdgcn_perm(uu[1], uu[0], 0x07060302u);
    pk.y = __builtin_amdgcn_perm(uu[3], uu[2], 0x07060302u);
    *(uint2*)(hT + (size_t)cc * N_NODES + r0 + q * 4) = pk;
  }
}

// K1c: ML = max(f_dstL)  (single block)
__global__ __launch_bounds__(256) void k_max(const float* __restrict__ fdstL,
                                             float* __restrict__ ML) {
  float m = -3.0e38f;
  for (int i = threadIdx.x; i < N_NODES; i += 256) m = fmaxf(m, fdstL[i]);
#pragma unroll
  for (int off = 32; off > 0; off >>= 1) m = fmaxf(m, __shfl_xor(m, off, 64));
  __shared__ float sm[4];
  if ((threadIdx.x & 63) == 0) sm[threadIdx.x >> 6] = m;
  __syncthreads();
  if (threadIdx.x == 0) ML[0] = fmaxf(fmaxf(sm[0], sm[1]), fmaxf(sm[2], sm[3]));
}

// K2: attention partials. Grid = 512 row-blocks x JSPLIT j-slabs (4096
// blocks, 4 waves each). Each wave covers 256 cols (4 windows of 64).
// All 16 VMEM loads of a window are issued before the compute.
// Writes num[js][i][c], den[js][i]; k_merge divides + ELU.
__global__ __launch_bounds__(256) void k_attn(const int* __restrict__ adj,
                                              const unsigned short* __restrict__ hT,
                                              const float* __restrict__ fsrcL,
                                              const float* __restrict__ fdstL,
                                              const float* __restrict__ MLp,
                                              float* __restrict__ num,
                                              float* __restrict__ den) {
  const int lane = threadIdx.x & 63;
  const int wv = threadIdx.x >> 6;  // 0..3
  const int rb = blockIdx.x >> 3;
  const int js = blockIdx.x & 7;
  const int i0 = rb * 16;
  const int m = lane & 15;  // A-row / B-col index
  const int g = lane >> 4;  // k-group 0..3

  const float MLv = MLp[0];
  const float fs = fsrcL[i0 + m];
  const float xm = fs + MLv;
  const float mL = fmaxf(xm, 0.2f * xm);  // fixed per-row max (log2 domain)

  f32x4 acc0{}, acc1{}, acc2{}, acc3{};
  float lpart = 0.f;

  const int* adjrow = adj + (size_t)(i0 + m) * N_NODES;
  const unsigned short* hT0 = hT + (size_t)m * N_NODES;

  const int jbeg = js * (N_NODES / JSPLIT) + wv * 256;
  for (int j0 = jbeg; j0 < jbeg + 256; j0 += 64) {
    const int jb0 = j0 + g * 8;
    const int jb1 = j0 + 32 + g * 8;
    // ---- all loads for this 64-col window ----
    int4 a00 = *(const int4*)(adjrow + jb0);
    int4 a01 = *(const int4*)(adjrow + jb0 + 4);
    int4 a10 = *(const int4*)(adjrow + jb1);
    int4 a11 = *(const int4*)(adjrow + jb1 + 4);
    float4 d00 = *(const float4*)(fdstL + jb0);
    float4 d01 = *(const float4*)(fdstL + jb0 + 4);
    float4 d10 = *(const float4*)(fdstL + jb1);
    float4 d11 = *(const float4*)(fdstL + jb1 + 4);
    bf16x8 b00 = *(const bf16x8*)(hT0 + jb0);
    bf16x8 b01 = *(const bf16x8*)(hT0 + (size_t)16 * N_NODES + jb0);
    bf16x8 b02 = *(const bf16x8*)(hT0 + (size_t)32 * N_NODES + jb0);
    bf16x8 b03 = *(const bf16x8*)(hT0 + (size_t)48 * N_NODES + jb0);
    bf16x8 b10 = *(const bf16x8*)(hT0 + jb1);
    bf16x8 b11 = *(const bf16x8*)(hT0 + (size_t)16 * N_NODES + jb1);
    bf16x8 b12 = *(const bf16x8*)(hT0 + (size_t)32 * N_NODES + jb1);
    bf16x8 b13 = *(const bf16x8*)(hT0 + (size_t)48 * N_NODES + jb1);
    // ---- compute s=0 ----
    {
      const int av[8] = {a00.x, a00.y, a00.z, a00.w, a01.x, a01.y, a01.z, a01.w};
      const float dv[8] = {d00.x, d00.y, d00.z, d00.w, d01.x, d01.y, d01.z, d01.w};
      unsigned u[8];
#pragma unroll
      for (int t = 0; t < 8; t++) {
        float x = fs + dv[t];
        float y = fmaxf(x, 0.2f * x) - mL;
        float p = __builtin_amdgcn_exp2f(y);
        p = av[t] ? p : 0.0f;
        lpart += p;
        u[t] = __float_as_uint(p) + 0x8000u;
      }
      union { unsigned w[4]; bf16x8 v; } pc;
      pc.w[0] = __builtin_amdgcn_perm(u[1], u[0], 0x07060302u);
      pc.w[1] = __builtin_amdgcn_perm(u[3], u[2], 0x07060302u);
      pc.w[2] = __builtin_amdgcn_perm(u[5], u[4], 0x07060302u);
      pc.w[3] = __builtin_amdgcn_perm(u[7], u[6], 0x07060302u);
      acc0 = __builtin_amdgcn_mfma_f32_16x16x32_bf16(pc.v, b00, acc0, 0, 0, 0);
      acc1 = __builtin_amdgcn_mfma_f32_16x16x32_bf16(pc.v, b01, acc1, 0, 0, 0);
      acc2 = __builtin_amdgcn_mfma_f32_16x16x32_bf16(pc.v, b02, acc2, 0, 0, 0);
      acc3 = __builtin_amdgcn_mfma_f32_16x16x32_bf16(pc.v, b03, acc3, 0, 0, 0);
    }
    // ---- compute s=1 ----
    {
      const int av[8] = {a10.x, a10.y, a10.z, a10.w, a11.x, a11.y, a11.z, a11.w};
      const float dv[8] = {d10.x, d10.y, d10.z, d10.w, d11.x, d11.y, d11.z, d11.w};
      unsigned u[8];
#pragma unroll
      for (int t = 0; t < 8; t++) {
        float x = fs + dv[t];
        float y = fmaxf(x, 0.2f * x) - mL;
        float p = __builtin_amdgcn_exp2f(y);
        p = av[t] ? p : 0.0f;
        lpart += p;
        u[t] = __float_as_uint(p) + 0x8000u;
      }
      union { unsigned w[4]; bf16x8 v; } pc;
      pc.w[0] = __builtin_amdgcn_perm(u[1], u[0], 0x07060302u);
      pc.w[1] = __builtin_amdgcn_perm(u[3], u[2], 0x07060302u);
      pc.w[2] = __builtin_amdgcn_perm(u[5], u[4], 0x07060302u);
      pc.w[3] = __builtin_amdgcn_perm(u[7], u[6], 0x07060302u);
      acc0 = __builtin_amdgcn_mfma_f32_16x16x32_bf16(pc.v, b10, acc0, 0, 0, 0);
      acc1 = __builtin_amdgcn_mfma_f32_16x16x32_bf16(pc.v, b11, acc1, 0, 0, 0);
      acc2 = __builtin_amdgcn_mfma_f32_16x16x32_bf16(pc.v, b12, acc2, 0, 0, 0);
      acc3 = __builtin_amdgcn_mfma_f32_16x16x32_bf16(pc.v, b13, acc3, 0, 0, 0);
    }
  }

  // l: reduce across the 4 k-groups (lanes sharing m)
  lpart += __shfl_xor(lpart, 16, 64);
  lpart += __shfl_xor(lpart, 32, 64);

  __shared__ float accbuf[4][16][64];
  __shared__ float lbuf[4][16];
#pragma unroll
  for (int r = 0; r < 4; r++) {
    accbuf[wv][g * 4 + r][0 + m]  = acc0[r];
    accbuf[wv][g * 4 + r][16 + m] = acc1[r];
    accbuf[wv][g * 4 + r][32 + m] = acc2[r];
    accbuf[wv][g * 4 + r][48 + m] = acc3[r];
  }
  if (lane < 16) lbuf[wv][lane] = lpart;
  __syncthreads();

#pragma unroll
  for (int q = 0; q < 4; q++) {
    int idx = q * 256 + threadIdx.x;
    int r = idx >> 6, c = idx & 63;
    float ssum = accbuf[0][r][c] + accbuf[1][r][c] + accbuf[2][r][c] + accbuf[3][r][c];
    num[((size_t)js * N_NODES + i0 + r) * OUT_F + c] = ssum;
  }
  if (threadIdx.x < 16) {
    den[(size_t)js * N_NODES + i0 + threadIdx.x] =
        lbuf[0][threadIdx.x] + lbuf[1][threadIdx.x] + lbuf[2][threadIdx.x] + lbuf[3][threadIdx.x];
  }
}

// K3: merge partials, divide, ELU.
__global__ __launch_bounds__(256) void k_merge(const float* __restrict__ num,
                                               const float* __restrict__ den,
                                               float* __restrict__ out) {
  const int idx = blockIdx.x * 256 + threadIdx.x;  // over N*OUT_F
  const int i = idx >> 6;
  float s = 0.f, l = 0.f;
#pragma unroll
  for (int js = 0; js < JSPLIT; js++) {
    s += num[((size_t)js * N_NODES) * OUT_F + idx];
    l += den[(size_t)js * N_NODES + i];
  }
  float v = s / l;
  out[idx] = v > 0.f ? v : __builtin_amdgcn_exp2f(v * LOG2E) - 1.f;
}

extern "C" void kernel_launch(void* const* d_in, const int* in_sizes, int n_in,
                              void* d_out, int out_size, void* d_ws, size_t ws_size,
                              hipStream_t stream) {
  const float* input = (const float*)d_in[0];
  const int* adj = (const int*)d_in[1];
  const float* W = (const float*)d_in[2];
  const float* a = (const float*)d_in[3];
  float* out = (float*)d_out;

  char* ws = (char*)d_ws;
  unsigned short* hT = (unsigned short*)ws;                  // 1 MB
  float* fsrcL = (float*)(ws + (1u << 20));                  // 32 KB
  float* fdstL = (float*)(ws + (1u << 20) + 32 * 1024);      // 32 KB
  float* ML = (float*)(ws + (1u << 20) + 64 * 1024);         // 4 B
  float* num = (float*)(ws + (2u << 20));                    // 16 MB
  float* den = (float*)(ws + (20u << 20));                   // 256 KB

  k_gemm<<<N_NODES / 16, 256, 0, stream>>>(input, W, a, hT, fsrcL, fdstL);
  k_max<<<1, 256, 0, stream>>>(fdstL, ML);
  k_attn<<<(N_NODES / 16) * JSPLIT, 256, 0, stream>>>(adj, hT, fsrcL, fdstL, ML, num, den);
  k_merge<<<N_NODES * OUT_F / 256, 256, 0, stream>>>(num, den, out);
}